// Round 15
// baseline (290.198 us; speedup 1.0000x reference)
//
#include <hip/hip_runtime.h>
#include <hip/hip_bf16.h>

#define N_NODES 50000
#define N_EDGES 640000
#define DUMMY   N_NODES
#define PAD_SSRC 990000   // u16 slots; E + 7*N upper bound
#define ST 50048          // cnt8 stride (per-key histogram copy)
// FEAT = EMB = 128, HID = 512, B = 32

typedef __attribute__((ext_vector_type(8))) short short8;   // 8 x bf16 (4 VGPRs)
typedef __attribute__((ext_vector_type(4))) float floatx4;  // MFMA C/D

__device__ __forceinline__ float bf2f(unsigned short u) {
    return __uint_as_float(((unsigned int)u) << 16);
}
__device__ __forceinline__ unsigned short f2bf(float x) {
    unsigned int u = __float_as_uint(x);
    u = (u + 0x7fffu + ((u >> 16) & 1u)) >> 16;   // RNE
    return (unsigned short)u;
}

// ---- fused prep: x->bf16 | pack weights | zero cnt8 | message_embed | fill ssrc pad | dummy row | total=0 ----
__global__ void __launch_bounds__(256) prep_k(const float4* __restrict__ x4,
                                              ushort4* __restrict__ xb4,
                                              const float* __restrict__ W0,
                                              const float* __restrict__ W1,
                                              const float* __restrict__ W2,
                                              const float* __restrict__ W3,
                                              unsigned short* __restrict__ T0,
                                              unsigned short* __restrict__ T1,
                                              unsigned short* __restrict__ T2,
                                              unsigned short* __restrict__ T3,
                                              int* __restrict__ cnt8,
                                              const float* __restrict__ lh,
                                              const float* __restrict__ Wp,
                                              const float* __restrict__ bp,
                                              unsigned short* __restrict__ meb,
                                              unsigned short* __restrict__ ssrc,
                                              unsigned short* __restrict__ tbf,
                                              int* __restrict__ total) {
    int b = blockIdx.x, tid = threadIdx.x;
    if (b < 6250) {                      // cast x to bf16: 1.6M float4
        int i = b * 256 + tid;
        float4 v = x4[i];
        ushort4 o;
        o.x = f2bf(v.x); o.y = f2bf(v.y); o.z = f2bf(v.z); o.w = f2bf(v.w);
        xb4[i] = o;
    } else if (b < 6506) {               // pack weights transposed: 65536
        int idx = (b - 6250) * 256 + tid;
        int w = idx >> 14;
        int r = idx & 16383;
        int n = r >> 7, k = r & 127;
        const float* W = (w == 0) ? W0 : (w == 1) ? W1 : (w == 2) ? W2 : W3;
        unsigned short* T = (w == 0) ? T0 : (w == 1) ? T1 : (w == 2) ? T2 : T3;
        T[r] = f2bf(W[k * 128 + n]);
    } else if (b < 8070) {               // zero cnt8: 8*ST = 400384 ints (1564 blocks)
        int i = (b - 6506) * 256 + tid;
        cnt8[i] = 0;                     // 1564*256 == 400384 exactly
    } else if (b < 8086) {               // message embed: 4096 outputs
        int o = (b - 8070) * 256 + tid;
        int i = o >> 7, c = o & 127;
        float acc = bp[c];
        const float4* lr = (const float4*)(lh + i * 512);
        #pragma unroll 4
        for (int k4 = 0; k4 < 128; k4++) {
            float4 v = lr[k4];
            acc += v.x * Wp[(4 * k4 + 0) * 128 + c] + v.y * Wp[(4 * k4 + 1) * 128 + c]
                 + v.z * Wp[(4 * k4 + 2) * 128 + c] + v.w * Wp[(4 * k4 + 3) * 128 + c];
        }
        meb[o] = f2bf(acc);
    } else if (b < 10020) {              // fill padded ssrc with DUMMY (u16 pairs): 495000 u32
        int i = (b - 8086) * 256 + tid;
        if (i < PAD_SSRC / 2) ((unsigned int*)ssrc)[i] = 0xC350C350u;
    } else {                             // zero dummy table row + total
        if (tid < 128) tbf[(size_t)DUMMY * 128 + tid] = 0;
        else if (tid == 128) *total = 0;
    }
}

// ---- histogram into per-key (pseudo-XCD) private copies; rank packs (r,key) ----
__global__ void __launch_bounds__(256) hist_k(const int* __restrict__ dst,
                                              int* __restrict__ cnt8,
                                              int* __restrict__ rank) {
    int e = blockIdx.x * 256 + threadIdx.x;   // exactly 640000
    int k = blockIdx.x & 7;
    int r = atomicAdd(&cnt8[k * ST + dst[e]], 1);
    rank[e] = (r << 3) | k;
}

// ---- shared gemm_dual body ----
__device__ __forceinline__ void gemm_dual_body(int bid, int tid,
                                               const unsigned short* __restrict__ A,
                                               const unsigned short* __restrict__ BtRel,
                                               const unsigned short* __restrict__ BtRoot,
                                               unsigned short* __restrict__ Trel,
                                               unsigned short* __restrict__ Rootb, int M) {
    int wid = tid >> 6, lane = tid & 63;
    int r0 = bid * 64 + wid * 16;
    int m = lane & 15, g = lane >> 4;
    int row = r0 + m;
    int rowc = (row < M) ? row : (M - 1);
    short8 a[4];
    #pragma unroll
    for (int kt = 0; kt < 4; kt++)
        a[kt] = *(const short8*)(A + (size_t)rowc * 128 + kt * 32 + g * 8);
    floatx4 accR[8], accO[8];
    #pragma unroll
    for (int ct = 0; ct < 8; ct++) {
        accR[ct] = (floatx4)(0.f);
        accO[ct] = (floatx4)(0.f);
    }
    #pragma unroll
    for (int ct = 0; ct < 8; ct++) {
        const unsigned short* br = BtRel  + (size_t)(ct * 16 + m) * 128 + g * 8;
        const unsigned short* bo = BtRoot + (size_t)(ct * 16 + m) * 128 + g * 8;
        #pragma unroll
        for (int kt = 0; kt < 4; kt++) {
            short8 bR = *(const short8*)(br + kt * 32);
            accR[ct] = __builtin_amdgcn_mfma_f32_16x16x32_bf16(a[kt], bR, accR[ct], 0, 0, 0);
            short8 bO = *(const short8*)(bo + kt * 32);
            accO[ct] = __builtin_amdgcn_mfma_f32_16x16x32_bf16(a[kt], bO, accO[ct], 0, 0, 0);
        }
    }
    // C/D layout: col = lane&15, row = (lane>>4)*4 + reg
    #pragma unroll
    for (int ct = 0; ct < 8; ct++) {
        #pragma unroll
        for (int rg = 0; rg < 4; rg++) {
            int ro = r0 + g * 4 + rg;
            if (ro < M) {
                int co = ct * 16 + m;
                Trel[(size_t)ro * 128 + co]  = f2bf(accR[ct][rg]);
                Rootb[(size_t)ro * 128 + co] = f2bf(accO[ct][rg]);
            }
        }
    }
}

// ---- merged: allocator w/ per-key prefix (blocks 0..195) | layer-1 dual GEMM ----
__global__ void __launch_bounds__(256) allocgemm_k(int* __restrict__ cnt8,
                                                   int* __restrict__ cnt,
                                                   int* __restrict__ prow,
                                                   int* __restrict__ total,
                                                   const unsigned short* __restrict__ A,
                                                   const unsigned short* __restrict__ BtRel,
                                                   const unsigned short* __restrict__ BtRoot,
                                                   unsigned short* __restrict__ Trel,
                                                   unsigned short* __restrict__ Rootb) {
    if (blockIdx.x < 196) {
        __shared__ int sm[256];
        __shared__ int base_s;
        int t = threadIdx.x;
        int i = blockIdx.x * 256 + t;
        int tot = 0;
        if (i < N_NODES) {
            int run = 0;
            #pragma unroll
            for (int x = 0; x < 8; x++) {
                int v = cnt8[x * ST + i];
                cnt8[x * ST + i] = run;    // sub-bucket base
                run += v;
            }
            tot = run;
            cnt[i] = tot;
        }
        int pc = (tot + 7) & ~7;
        sm[t] = pc;
        __syncthreads();
        for (int off = 1; off < 256; off <<= 1) {
            int v = (t >= off) ? sm[t - off] : 0;
            __syncthreads();
            sm[t] += v;
            __syncthreads();
        }
        if (t == 255) base_s = atomicAdd(total, sm[255]);
        __syncthreads();
        if (i < N_NODES) prow[i] = base_s + sm[t] - pc;
    } else {
        gemm_dual_body(blockIdx.x - 196, threadIdx.x, A, BtRel, BtRoot, Trel, Rootb, N_NODES);
    }
}

// ---- placement: key-local sub-bucket scatter (no atomic) ----
__global__ void __launch_bounds__(256) place_k(const int* __restrict__ src,
                                               const int* __restrict__ dst,
                                               const int* __restrict__ prow,
                                               const int* __restrict__ cnt8,
                                               const int* __restrict__ rank,
                                               unsigned short* __restrict__ ssrc) {
    int e = blockIdx.x * 256 + threadIdx.x;
    if (e < N_EDGES) {
        int d = dst[e];
        int rk = rank[e];
        int k = rk & 7, r = rk >> 3;
        ssrc[prow[d] + cnt8[k * ST + d] + r] = (unsigned short)src[e];
    }
}

// ---- standalone dual GEMM (layer 2) ----
__global__ void __launch_bounds__(256) gemm_dual_k(const unsigned short* __restrict__ A,
                                                   const unsigned short* __restrict__ BtRel,
                                                   const unsigned short* __restrict__ BtRoot,
                                                   unsigned short* __restrict__ Trel,
                                                   unsigned short* __restrict__ Rootb, int M) {
    gemm_dual_body(blockIdx.x, threadIdx.x, A, BtRel, BtRoot, Trel, Rootb, M);
}

// ---- gather-aggregate v7: 2 rows per gather instruction (ushort4/lane), 16 edges/round ----
__global__ void __launch_bounds__(256) agg_k(const int* __restrict__ prow,
                                             const int* __restrict__ cnt,
                                             const unsigned short* __restrict__ ssrc,
                                             const unsigned short* __restrict__ t,
                                             const unsigned short* __restrict__ rootb,
                                             const float* __restrict__ bias,
                                             unsigned short* __restrict__ hout) {
    int node = blockIdx.x * 4 + (threadIdx.x >> 6);
    if (node >= N_NODES) return;
    int lane = threadIdx.x & 63;
    int fl = lane & 31;                    // feature group
    int sh = (lane & 32) >> 1;             // 0 for even-edge half, 16 for odd-edge half
    int beg = prow[node];
    int deg = cnt[node];
    int endp = beg + ((deg + 7) & ~7);
    const unsigned short* tf = t + fl * 4;
    float a0=0.f,a1=0.f,a2=0.f,a3=0.f;
    float b0=0.f,b1=0.f,b2=0.f,b3=0.f;
    for (int e = beg; e < endp; e += 16) {
        uint4 w0 = *(const uint4*)(ssrc + e);
        uint4 w1 = (e + 8 < endp) ? *(const uint4*)(ssrc + e + 8)
                                  : make_uint4(0xC350C350u, 0xC350C350u, 0xC350C350u, 0xC350C350u);
        int i0 = (int)((w0.x >> sh) & 0xffffu);
        int i1 = (int)((w0.y >> sh) & 0xffffu);
        int i2 = (int)((w0.z >> sh) & 0xffffu);
        int i3 = (int)((w0.w >> sh) & 0xffffu);
        int i4 = (int)((w1.x >> sh) & 0xffffu);
        int i5 = (int)((w1.y >> sh) & 0xffffu);
        int i6 = (int)((w1.z >> sh) & 0xffffu);
        int i7 = (int)((w1.w >> sh) & 0xffffu);
        ushort4 u0 = *(const ushort4*)(tf + (size_t)i0 * 128);
        ushort4 u1 = *(const ushort4*)(tf + (size_t)i1 * 128);
        ushort4 u2 = *(const ushort4*)(tf + (size_t)i2 * 128);
        ushort4 u3 = *(const ushort4*)(tf + (size_t)i3 * 128);
        ushort4 u4 = *(const ushort4*)(tf + (size_t)i4 * 128);
        ushort4 u5 = *(const ushort4*)(tf + (size_t)i5 * 128);
        ushort4 u6 = *(const ushort4*)(tf + (size_t)i6 * 128);
        ushort4 u7 = *(const ushort4*)(tf + (size_t)i7 * 128);
        a0 += bf2f(u0.x) + bf2f(u1.x);  a1 += bf2f(u0.y) + bf2f(u1.y);
        a2 += bf2f(u0.z) + bf2f(u1.z);  a3 += bf2f(u0.w) + bf2f(u1.w);
        b0 += bf2f(u2.x) + bf2f(u3.x);  b1 += bf2f(u2.y) + bf2f(u3.y);
        b2 += bf2f(u2.z) + bf2f(u3.z);  b3 += bf2f(u2.w) + bf2f(u3.w);
        a0 += bf2f(u4.x) + bf2f(u5.x);  a1 += bf2f(u4.y) + bf2f(u5.y);
        a2 += bf2f(u4.z) + bf2f(u5.z);  a3 += bf2f(u4.w) + bf2f(u5.w);
        b0 += bf2f(u6.x) + bf2f(u7.x);  b1 += bf2f(u6.y) + bf2f(u7.y);
        b2 += bf2f(u6.z) + bf2f(u7.z);  b3 += bf2f(u6.w) + bf2f(u7.w);
    }
    a0 += b0; a1 += b1; a2 += b2; a3 += b3;
    a0 += __shfl_xor(a0, 32);
    a1 += __shfl_xor(a1, 32);
    a2 += __shfl_xor(a2, 32);
    a3 += __shfl_xor(a3, 32);
    if ((lane & 32) == 0) {
        float inv = 1.f / fmaxf((float)deg, 1.f);
        int f = fl * 4;
        ushort4 r = *(const ushort4*)(rootb + (size_t)node * 128 + f);
        float4 bb = *(const float4*)(bias + f);
        ushort4 o;
        o.x = f2bf(fmaxf(a0 * inv + bf2f(r.x) + bb.x, 0.f));
        o.y = f2bf(fmaxf(a1 * inv + bf2f(r.y) + bb.y, 0.f));
        o.z = f2bf(fmaxf(a2 * inv + bf2f(r.z) + bb.z, 0.f));
        o.w = f2bf(fmaxf(a3 * inv + bf2f(r.w) + bb.w, 0.f));
        *(ushort4*)(hout + (size_t)node * 128 + f) = o;
    }
}

// ---- scores MFMA GEMM fused with per-block column stats ----
__global__ void __launch_bounds__(256) scores_cs_k(const unsigned short* __restrict__ A,
                                                   const unsigned short* __restrict__ Bt,
                                                   float* __restrict__ S,
                                                   float* __restrict__ pm,
                                                   float* __restrict__ ps) {
    __shared__ float Sl[64][33];
    __shared__ float sm[256], ss[256];
    int tid = threadIdx.x;
    int wid = tid >> 6, lane = tid & 63;
    int r0 = blockIdx.x * 64 + wid * 16;
    int m = lane & 15, g = lane >> 4;
    int row = r0 + m;
    int rowc = (row < N_NODES) ? row : (N_NODES - 1);
    short8 a[4];
    #pragma unroll
    for (int kt = 0; kt < 4; kt++)
        a[kt] = *(const short8*)(A + (size_t)rowc * 128 + kt * 32 + g * 8);
    floatx4 acc[2];
    acc[0] = (floatx4)(0.f);
    acc[1] = (floatx4)(0.f);
    #pragma unroll
    for (int ct = 0; ct < 2; ct++) {
        const unsigned short* b = Bt + (size_t)(ct * 16 + m) * 128 + g * 8;
        #pragma unroll
        for (int kt = 0; kt < 4; kt++) {
            short8 bv = *(const short8*)(b + kt * 32);
            acc[ct] = __builtin_amdgcn_mfma_f32_16x16x32_bf16(a[kt], bv, acc[ct], 0, 0, 0);
        }
    }
    #pragma unroll
    for (int ct = 0; ct < 2; ct++) {
        #pragma unroll
        for (int rg = 0; rg < 4; rg++) {
            int lr = wid * 16 + g * 4 + rg;
            int ro = r0 + g * 4 + rg;
            Sl[lr][ct * 16 + m] = acc[ct][rg];
            if (ro < N_NODES) S[(size_t)ro * 32 + ct * 16 + m] = acc[ct][rg];
        }
    }
    __syncthreads();
    int col = tid & 31, sub = tid >> 5;
    int blkbase = blockIdx.x * 64;
    float mm = -3.4e38f, s = 0.f;
    for (int r = sub; r < 64; r += 8) {
        if (blkbase + r < N_NODES) {
            float v = Sl[r][col];
            if (v > mm) { s = s * __expf(mm - v) + 1.f; mm = v; }
            else        { s += __expf(v - mm); }
        }
    }
    sm[tid] = mm; ss[tid] = s;
    __syncthreads();
    for (int off = 128; off >= 32; off >>= 1) {
        if (tid < off) {
            float m2 = sm[tid + off], s2 = ss[tid + off];
            float M = fmaxf(sm[tid], m2);
            ss[tid] = ss[tid] * __expf(sm[tid] - M) + s2 * __expf(m2 - M);
            sm[tid] = M;
        }
        __syncthreads();
    }
    if (tid < 32) { pm[tid * 782 + blockIdx.x] = sm[tid]; ps[tid * 782 + blockIdx.x] = ss[tid]; }
}

// ---- merge: one block per column, reduce 782 chunks -> cm/cl[32] ----
__global__ void __launch_bounds__(256) merge_k(const float* __restrict__ pm,
                                               const float* __restrict__ ps,
                                               float* __restrict__ cmg,
                                               float* __restrict__ clg) {
    __shared__ float sm[256], ss[256];
    int col = blockIdx.x;
    int t = threadIdx.x;
    float m = -3.4e38f, s = 0.f;
    for (int c = t; c < 782; c += 256) {
        float m2 = pm[col * 782 + c], s2 = ps[col * 782 + c];
        float M = fmaxf(m, m2);
        s = s * __expf(m - M) + s2 * __expf(m2 - M);
        m = M;
    }
    sm[t] = m; ss[t] = s;
    __syncthreads();
    for (int off = 128; off > 0; off >>= 1) {
        if (t < off) {
            float m2 = sm[t + off], s2 = ss[t + off];
            float M = fmaxf(sm[t], m2);
            ss[t] = ss[t] * __expf(sm[t] - M) + s2 * __expf(m2 - M);
            sm[t] = M;
        }
        __syncthreads();
    }
    if (t == 0) { cmg[col] = sm[0]; clg[col] = logf(ss[0]); }
}

// ---- final: element-wise subtract, full grid ----
__global__ void __launch_bounds__(256) final_k(const float* __restrict__ S,
                                               const float* __restrict__ cmg,
                                               const float* __restrict__ clg,
                                               float* __restrict__ out) {
    __shared__ float cc[32];
    int t = threadIdx.x;
    if (t < 32) cc[t] = cmg[t] + clg[t];
    __syncthreads();
    int idx = blockIdx.x * 256 + t;
    if (idx < N_NODES * 32) {
        int b = idx & 31;
        out[idx] = S[idx] - cc[b];
    }
}

extern "C" void kernel_launch(void* const* d_in, const int* in_sizes, int n_in,
                              void* d_out, int out_size, void* d_ws, size_t ws_size,
                              hipStream_t stream) {
    const float* x       = (const float*)d_in[0];
    const int*   ei      = (const int*)d_in[1];
    const float* lh      = (const float*)d_in[2];
    const float* W1_rel  = (const float*)d_in[3];
    const float* W1_root = (const float*)d_in[4];
    const float* b1      = (const float*)d_in[5];
    const float* W2_rel  = (const float*)d_in[6];
    const float* W2_root = (const float*)d_in[7];
    const float* b2      = (const float*)d_in[8];
    const float* Wp      = (const float*)d_in[9];
    const float* bp      = (const float*)d_in[10];
    float* out = (float*)d_out;
    float* ws  = (float*)d_ws;

    // workspace layout (float-element offsets; 16B alignment where needed)
    unsigned short* xb    = (unsigned short*)(ws);              // 3.2M fl
    unsigned short* tbf   = (unsigned short*)(ws + 3200000);    // 50001 rows -> 3,200,064 fl
    unsigned short* rootb = (unsigned short*)(ws + 6400064);    // 3.2M fl
    unsigned short* hb    = (unsigned short*)(ws + 9600064);    // 3.2M fl
    unsigned short* Wt1r  = (unsigned short*)(ws + 12800064);   // 8192 fl each
    unsigned short* Wt1o  = (unsigned short*)(ws + 12808256);
    unsigned short* Wt2r  = (unsigned short*)(ws + 12816448);
    unsigned short* Wt2o  = (unsigned short*)(ws + 12824640);
    unsigned short* MEb   = (unsigned short*)(ws + 12832832);   // 2048 fl
    float* pm   = ws + 12834880;                                // 25,024
    float* ps   = ws + 12859904;                                // 25,024
    float* cmg  = ws + 12884928;                                // 32
    float* clg  = ws + 12884960;                                // 32
    int*   cnt  = (int*)(ws + 12884992);                        // 50,000
    int*   prow = (int*)(ws + 12934992);                        // 50,001
    int*   total= (int*)(ws + 12984993);                        // 1
    int*   rank = (int*)(ws + 12984996);                        // 640,000
    int*   cnt8 = (int*)(ws + 13624996);                        // 8*ST = 400,384
    unsigned short* ssrc = (unsigned short*)(ws + 14025380);    // 990,000 u16 (16B-aligned)
    float* S    = ws + 14520380;                                // 1,600,000

    const int* srcp = ei;
    const int* dstp = ei + N_EDGES;

    const int e_grid   = (N_EDGES + 255) / 256;      // 2500
    const int ew_grid  = (N_NODES * 32 + 255) / 256; // 6250
    const int agg_grid = (N_NODES + 3) / 4;          // 12500
    const int mm_grid  = (N_NODES + 63) / 64;        // 782

    // 1. fused prep
    prep_k<<<10021, 256, 0, stream>>>((const float4*)x, (ushort4*)xb,
                                      W1_rel, W1_root, W2_rel, W2_root,
                                      Wt1r, Wt1o, Wt2r, Wt2o,
                                      cnt8, lh, Wp, bp, MEb, ssrc, tbf, total);

    // 2. histogram into per-key private copies + rank
    hist_k<<<e_grid, 256, 0, stream>>>(dstp, cnt8, rank);

    // 3. allocator (sum 8 copies, per-key prefix, region grab) | layer-1 dual GEMM
    allocgemm_k<<<196 + mm_grid, 256, 0, stream>>>(cnt8, cnt, prow, total,
                                                   xb, Wt1r, Wt1o, tbf, rootb);

    // 4. placement (key-local sub-buckets)
    place_k<<<e_grid, 256, 0, stream>>>(srcp, dstp, prow, cnt8, rank, ssrc);

    // 5. layer-1 aggregate
    agg_k<<<agg_grid, 256, 0, stream>>>(prow, cnt, ssrc, tbf, rootb, b1, hb);

    // 6. layer-2 dual GEMM
    gemm_dual_k<<<mm_grid, 256, 0, stream>>>(hb, Wt2r, Wt2o, tbf, rootb, N_NODES);

    // 7. layer-2 aggregate
    agg_k<<<agg_grid, 256, 0, stream>>>(prow, cnt, ssrc, tbf, rootb, b2, hb);

    // 8. scores GEMM + fused per-block column stats
    scores_cs_k<<<mm_grid, 256, 0, stream>>>(hb, MEb, S, pm, ps);

    // 9. merge column stats (32 blocks)
    merge_k<<<32, 256, 0, stream>>>(pm, ps, cmg, clg);

    // 10. final subtract (full grid)
    final_k<<<ew_grid, 256, 0, stream>>>(S, cmg, clg, out);
}

// Round 16
// 282.249 us; speedup vs baseline: 1.0282x; 1.0282x over previous
//
#include <hip/hip_runtime.h>
#include <hip/hip_bf16.h>

#define N_NODES 50000
#define N_EDGES 640000
#define DUMMY   N_NODES
#define PAD_SSRC 990000   // u16 slots; E + 7*N upper bound
// FEAT = EMB = 128, HID = 512, B = 32

typedef __attribute__((ext_vector_type(8))) short short8;   // 8 x bf16 (4 VGPRs)
typedef __attribute__((ext_vector_type(4))) float floatx4;  // MFMA C/D

__device__ __forceinline__ float bf2f(unsigned short u) {
    return __uint_as_float(((unsigned int)u) << 16);
}
__device__ __forceinline__ unsigned short f2bf(float x) {
    unsigned int u = __float_as_uint(x);
    u = (u + 0x7fffu + ((u >> 16) & 1u)) >> 16;   // RNE
    return (unsigned short)u;
}
__device__ __forceinline__ unsigned char f2f8(float x) {
    int pk = __builtin_amdgcn_cvt_pk_fp8_f32(x, x, 0, false);  // OCP e4m3 on gfx950
    return (unsigned char)(pk & 0xff);
}

// ---- fused prep: x->bf16 | pack weights | zero cnt | message_embed | fill ssrc pad | dummy row | total=0 ----
__global__ void __launch_bounds__(256) prep_k(const float4* __restrict__ x4,
                                              ushort4* __restrict__ xb4,
                                              const float* __restrict__ W0,
                                              const float* __restrict__ W1,
                                              const float* __restrict__ W2,
                                              const float* __restrict__ W3,
                                              unsigned short* __restrict__ T0,
                                              unsigned short* __restrict__ T1,
                                              unsigned short* __restrict__ T2,
                                              unsigned short* __restrict__ T3,
                                              int* __restrict__ cnt,
                                              const float* __restrict__ lh,
                                              const float* __restrict__ Wp,
                                              const float* __restrict__ bp,
                                              unsigned short* __restrict__ meb,
                                              unsigned short* __restrict__ ssrc,
                                              unsigned char* __restrict__ tbf,
                                              int* __restrict__ total) {
    int b = blockIdx.x, tid = threadIdx.x;
    if (b < 6250) {                      // cast x to bf16: 1.6M float4
        int i = b * 256 + tid;
        float4 v = x4[i];
        ushort4 o;
        o.x = f2bf(v.x); o.y = f2bf(v.y); o.z = f2bf(v.z); o.w = f2bf(v.w);
        xb4[i] = o;
    } else if (b < 6506) {               // pack weights transposed: 65536
        int idx = (b - 6250) * 256 + tid;
        int w = idx >> 14;
        int r = idx & 16383;
        int n = r >> 7, k = r & 127;
        const float* W = (w == 0) ? W0 : (w == 1) ? W1 : (w == 2) ? W2 : W3;
        unsigned short* T = (w == 0) ? T0 : (w == 1) ? T1 : (w == 2) ? T2 : T3;
        T[r] = f2bf(W[k * 128 + n]);
    } else if (b < 6702) {               // zero cnt: 50000
        int i = (b - 6506) * 256 + tid;
        if (i < N_NODES) cnt[i] = 0;
    } else if (b < 6718) {               // message embed: 4096 outputs
        int o = (b - 6702) * 256 + tid;
        int i = o >> 7, c = o & 127;
        float acc = bp[c];
        const float4* lr = (const float4*)(lh + i * 512);
        #pragma unroll 4
        for (int k4 = 0; k4 < 128; k4++) {
            float4 v = lr[k4];
            acc += v.x * Wp[(4 * k4 + 0) * 128 + c] + v.y * Wp[(4 * k4 + 1) * 128 + c]
                 + v.z * Wp[(4 * k4 + 2) * 128 + c] + v.w * Wp[(4 * k4 + 3) * 128 + c];
        }
        meb[o] = f2bf(acc);
    } else if (b < 8653) {               // fill padded ssrc with DUMMY (u16 pairs): 495000 u32
        int i = (b - 6718) * 256 + tid;
        if (i < PAD_SSRC / 2) ((unsigned int*)ssrc)[i] = 0xC350C350u;
    } else {                             // zero dummy fp8 row (128 B) + total
        if (tid < 32) ((unsigned int*)(tbf + (size_t)DUMMY * 128))[tid] = 0;
        else if (tid == 32) *total = 0;
    }
}

// ---- histogram + per-edge rank ----
__global__ void __launch_bounds__(256) hist_k(const int* __restrict__ dst,
                                              int* __restrict__ cnt,
                                              int* __restrict__ rank) {
    int e = blockIdx.x * 256 + threadIdx.x;   // exactly 640000
    rank[e] = atomicAdd(&cnt[dst[e]], 1);
}

// ---- shared gemm_dual body: Trel = fp8(A@Wrel), Rootb = bf16(A@Wroot) ----
__device__ __forceinline__ void gemm_dual_body(int bid, int tid,
                                               const unsigned short* __restrict__ A,
                                               const unsigned short* __restrict__ BtRel,
                                               const unsigned short* __restrict__ BtRoot,
                                               unsigned char* __restrict__ Trel,
                                               unsigned short* __restrict__ Rootb, int M) {
    int wid = tid >> 6, lane = tid & 63;
    int r0 = bid * 64 + wid * 16;
    int m = lane & 15, g = lane >> 4;
    int row = r0 + m;
    int rowc = (row < M) ? row : (M - 1);
    short8 a[4];
    #pragma unroll
    for (int kt = 0; kt < 4; kt++)
        a[kt] = *(const short8*)(A + (size_t)rowc * 128 + kt * 32 + g * 8);
    floatx4 accR[8], accO[8];
    #pragma unroll
    for (int ct = 0; ct < 8; ct++) {
        accR[ct] = (floatx4)(0.f);
        accO[ct] = (floatx4)(0.f);
    }
    #pragma unroll
    for (int ct = 0; ct < 8; ct++) {
        const unsigned short* br = BtRel  + (size_t)(ct * 16 + m) * 128 + g * 8;
        const unsigned short* bo = BtRoot + (size_t)(ct * 16 + m) * 128 + g * 8;
        #pragma unroll
        for (int kt = 0; kt < 4; kt++) {
            short8 bR = *(const short8*)(br + kt * 32);
            accR[ct] = __builtin_amdgcn_mfma_f32_16x16x32_bf16(a[kt], bR, accR[ct], 0, 0, 0);
            short8 bO = *(const short8*)(bo + kt * 32);
            accO[ct] = __builtin_amdgcn_mfma_f32_16x16x32_bf16(a[kt], bO, accO[ct], 0, 0, 0);
        }
    }
    // C/D layout: col = lane&15, row = (lane>>4)*4 + reg
    #pragma unroll
    for (int ct = 0; ct < 8; ct++) {
        #pragma unroll
        for (int rg = 0; rg < 4; rg++) {
            int ro = r0 + g * 4 + rg;
            if (ro < M) {
                int co = ct * 16 + m;
                Trel[(size_t)ro * 128 + co]  = f2f8(accR[ct][rg]);
                Rootb[(size_t)ro * 128 + co] = f2bf(accO[ct][rg]);
            }
        }
    }
}

// ---- merged: region allocator (blocks 0..195) | layer-1 dual GEMM (blocks 196..977) ----
__global__ void __launch_bounds__(256) allocgemm_k(const int* __restrict__ cnt,
                                                   int* __restrict__ prow,
                                                   int* __restrict__ total,
                                                   const unsigned short* __restrict__ A,
                                                   const unsigned short* __restrict__ BtRel,
                                                   const unsigned short* __restrict__ BtRoot,
                                                   unsigned char* __restrict__ Trel,
                                                   unsigned short* __restrict__ Rootb) {
    if (blockIdx.x < 196) {
        __shared__ int sm[256];
        __shared__ int base_s;
        int t = threadIdx.x;
        int i = blockIdx.x * 256 + t;
        int pc = (i < N_NODES) ? ((cnt[i] + 7) & ~7) : 0;
        sm[t] = pc;
        __syncthreads();
        for (int off = 1; off < 256; off <<= 1) {
            int v = (t >= off) ? sm[t - off] : 0;
            __syncthreads();
            sm[t] += v;
            __syncthreads();
        }
        if (t == 255) base_s = atomicAdd(total, sm[255]);
        __syncthreads();
        if (i < N_NODES) prow[i] = base_s + sm[t] - pc;
    } else {
        gemm_dual_body(blockIdx.x - 196, threadIdx.x, A, BtRel, BtRoot, Trel, Rootb, N_NODES);
    }
}

// ---- placement: no atomic (rank precomputed), plain u16 store ----
__global__ void __launch_bounds__(256) place_k(const int* __restrict__ src,
                                               const int* __restrict__ dst,
                                               const int* __restrict__ prow,
                                               const int* __restrict__ rank,
                                               unsigned short* __restrict__ ssrc) {
    int e = blockIdx.x * 256 + threadIdx.x;
    if (e < N_EDGES) {
        ssrc[prow[dst[e]] + rank[e]] = (unsigned short)src[e];
    }
}

// ---- standalone dual GEMM (layer 2) ----
__global__ void __launch_bounds__(256) gemm_dual_k(const unsigned short* __restrict__ A,
                                                   const unsigned short* __restrict__ BtRel,
                                                   const unsigned short* __restrict__ BtRoot,
                                                   unsigned char* __restrict__ Trel,
                                                   unsigned short* __restrict__ Rootb, int M) {
    gemm_dual_body(blockIdx.x, threadIdx.x, A, BtRel, BtRoot, Trel, Rootb, M);
}

// ---- gather-aggregate v8: fp8 table (128 B row = 2 lines), 2 rows/instr, 16 edges/round ----
// wave = node; lanes 0-31 even edges, 32-63 odd edges; lane covers features fl*4..fl*4+3
__global__ void __launch_bounds__(256) agg_k(const int* __restrict__ prow,
                                             const int* __restrict__ cnt,
                                             const unsigned short* __restrict__ ssrc,
                                             const unsigned char* __restrict__ t,
                                             const unsigned short* __restrict__ rootb,
                                             const float* __restrict__ bias,
                                             unsigned short* __restrict__ hout) {
    int node = blockIdx.x * 4 + (threadIdx.x >> 6);
    if (node >= N_NODES) return;
    int lane = threadIdx.x & 63;
    int fl = lane & 31;                    // feature group (4 feats)
    int sh = (lane & 32) >> 1;             // 0 = even-edge half, 16 = odd-edge half
    int beg = prow[node];
    int deg = cnt[node];
    int endp = beg + ((deg + 7) & ~7);
    const unsigned char* tf = t + fl * 4;
    float a0=0.f,a1=0.f,a2=0.f,a3=0.f;
    float b0=0.f,b1=0.f,b2=0.f,b3=0.f;
    for (int e = beg; e < endp; e += 16) {
        uint4 w0 = *(const uint4*)(ssrc + e);
        uint4 w1 = (e + 8 < endp) ? *(const uint4*)(ssrc + e + 8)
                                  : make_uint4(0xC350C350u, 0xC350C350u, 0xC350C350u, 0xC350C350u);
        int i0 = (int)((w0.x >> sh) & 0xffffu);
        int i1 = (int)((w0.y >> sh) & 0xffffu);
        int i2 = (int)((w0.z >> sh) & 0xffffu);
        int i3 = (int)((w0.w >> sh) & 0xffffu);
        int i4 = (int)((w1.x >> sh) & 0xffffu);
        int i5 = (int)((w1.y >> sh) & 0xffffu);
        int i6 = (int)((w1.z >> sh) & 0xffffu);
        int i7 = (int)((w1.w >> sh) & 0xffffu);
        unsigned int u0 = *(const unsigned int*)(tf + (size_t)i0 * 128);
        unsigned int u1 = *(const unsigned int*)(tf + (size_t)i1 * 128);
        unsigned int u2 = *(const unsigned int*)(tf + (size_t)i2 * 128);
        unsigned int u3 = *(const unsigned int*)(tf + (size_t)i3 * 128);
        unsigned int u4 = *(const unsigned int*)(tf + (size_t)i4 * 128);
        unsigned int u5 = *(const unsigned int*)(tf + (size_t)i5 * 128);
        unsigned int u6 = *(const unsigned int*)(tf + (size_t)i6 * 128);
        unsigned int u7 = *(const unsigned int*)(tf + (size_t)i7 * 128);
        a0 += __builtin_amdgcn_cvt_f32_fp8(u0, 0) + __builtin_amdgcn_cvt_f32_fp8(u1, 0);
        a1 += __builtin_amdgcn_cvt_f32_fp8(u0, 1) + __builtin_amdgcn_cvt_f32_fp8(u1, 1);
        a2 += __builtin_amdgcn_cvt_f32_fp8(u0, 2) + __builtin_amdgcn_cvt_f32_fp8(u1, 2);
        a3 += __builtin_amdgcn_cvt_f32_fp8(u0, 3) + __builtin_amdgcn_cvt_f32_fp8(u1, 3);
        b0 += __builtin_amdgcn_cvt_f32_fp8(u2, 0) + __builtin_amdgcn_cvt_f32_fp8(u3, 0);
        b1 += __builtin_amdgcn_cvt_f32_fp8(u2, 1) + __builtin_amdgcn_cvt_f32_fp8(u3, 1);
        b2 += __builtin_amdgcn_cvt_f32_fp8(u2, 2) + __builtin_amdgcn_cvt_f32_fp8(u3, 2);
        b3 += __builtin_amdgcn_cvt_f32_fp8(u2, 3) + __builtin_amdgcn_cvt_f32_fp8(u3, 3);
        a0 += __builtin_amdgcn_cvt_f32_fp8(u4, 0) + __builtin_amdgcn_cvt_f32_fp8(u5, 0);
        a1 += __builtin_amdgcn_cvt_f32_fp8(u4, 1) + __builtin_amdgcn_cvt_f32_fp8(u5, 1);
        a2 += __builtin_amdgcn_cvt_f32_fp8(u4, 2) + __builtin_amdgcn_cvt_f32_fp8(u5, 2);
        a3 += __builtin_amdgcn_cvt_f32_fp8(u4, 3) + __builtin_amdgcn_cvt_f32_fp8(u5, 3);
        b0 += __builtin_amdgcn_cvt_f32_fp8(u6, 0) + __builtin_amdgcn_cvt_f32_fp8(u7, 0);
        b1 += __builtin_amdgcn_cvt_f32_fp8(u6, 1) + __builtin_amdgcn_cvt_f32_fp8(u7, 1);
        b2 += __builtin_amdgcn_cvt_f32_fp8(u6, 2) + __builtin_amdgcn_cvt_f32_fp8(u7, 2);
        b3 += __builtin_amdgcn_cvt_f32_fp8(u6, 3) + __builtin_amdgcn_cvt_f32_fp8(u7, 3);
    }
    a0 += b0; a1 += b1; a2 += b2; a3 += b3;
    a0 += __shfl_xor(a0, 32);
    a1 += __shfl_xor(a1, 32);
    a2 += __shfl_xor(a2, 32);
    a3 += __shfl_xor(a3, 32);
    if ((lane & 32) == 0) {
        float inv = 1.f / fmaxf((float)deg, 1.f);
        int f = fl * 4;
        ushort4 r = *(const ushort4*)(rootb + (size_t)node * 128 + f);
        float4 bb = *(const float4*)(bias + f);
        ushort4 o;
        o.x = f2bf(fmaxf(a0 * inv + bf2f(r.x) + bb.x, 0.f));
        o.y = f2bf(fmaxf(a1 * inv + bf2f(r.y) + bb.y, 0.f));
        o.z = f2bf(fmaxf(a2 * inv + bf2f(r.z) + bb.z, 0.f));
        o.w = f2bf(fmaxf(a3 * inv + bf2f(r.w) + bb.w, 0.f));
        *(ushort4*)(hout + (size_t)node * 128 + f) = o;
    }
}

// ---- scores MFMA GEMM fused with per-block column stats ----
__global__ void __launch_bounds__(256) scores_cs_k(const unsigned short* __restrict__ A,
                                                   const unsigned short* __restrict__ Bt,
                                                   float* __restrict__ S,
                                                   float* __restrict__ pm,
                                                   float* __restrict__ ps) {
    __shared__ float Sl[64][33];
    __shared__ float sm[256], ss[256];
    int tid = threadIdx.x;
    int wid = tid >> 6, lane = tid & 63;
    int r0 = blockIdx.x * 64 + wid * 16;
    int m = lane & 15, g = lane >> 4;
    int row = r0 + m;
    int rowc = (row < N_NODES) ? row : (N_NODES - 1);
    short8 a[4];
    #pragma unroll
    for (int kt = 0; kt < 4; kt++)
        a[kt] = *(const short8*)(A + (size_t)rowc * 128 + kt * 32 + g * 8);
    floatx4 acc[2];
    acc[0] = (floatx4)(0.f);
    acc[1] = (floatx4)(0.f);
    #pragma unroll
    for (int ct = 0; ct < 2; ct++) {
        const unsigned short* b = Bt + (size_t)(ct * 16 + m) * 128 + g * 8;
        #pragma unroll
        for (int kt = 0; kt < 4; kt++) {
            short8 bv = *(const short8*)(b + kt * 32);
            acc[ct] = __builtin_amdgcn_mfma_f32_16x16x32_bf16(a[kt], bv, acc[ct], 0, 0, 0);
        }
    }
    #pragma unroll
    for (int ct = 0; ct < 2; ct++) {
        #pragma unroll
        for (int rg = 0; rg < 4; rg++) {
            int lr = wid * 16 + g * 4 + rg;
            int ro = r0 + g * 4 + rg;
            Sl[lr][ct * 16 + m] = acc[ct][rg];
            if (ro < N_NODES) S[(size_t)ro * 32 + ct * 16 + m] = acc[ct][rg];
        }
    }
    __syncthreads();
    int col = tid & 31, sub = tid >> 5;
    int blkbase = blockIdx.x * 64;
    float mm = -3.4e38f, s = 0.f;
    for (int r = sub; r < 64; r += 8) {
        if (blkbase + r < N_NODES) {
            float v = Sl[r][col];
            if (v > mm) { s = s * __expf(mm - v) + 1.f; mm = v; }
            else        { s += __expf(v - mm); }
        }
    }
    sm[tid] = mm; ss[tid] = s;
    __syncthreads();
    for (int off = 128; off >= 32; off >>= 1) {
        if (tid < off) {
            float m2 = sm[tid + off], s2 = ss[tid + off];
            float M = fmaxf(sm[tid], m2);
            ss[tid] = ss[tid] * __expf(sm[tid] - M) + s2 * __expf(m2 - M);
            sm[tid] = M;
        }
        __syncthreads();
    }
    if (tid < 32) { pm[tid * 782 + blockIdx.x] = sm[tid]; ps[tid * 782 + blockIdx.x] = ss[tid]; }
}

// ---- merge: one block per column, reduce 782 chunks -> cm/cl[32] ----
__global__ void __launch_bounds__(256) merge_k(const float* __restrict__ pm,
                                               const float* __restrict__ ps,
                                               float* __restrict__ cmg,
                                               float* __restrict__ clg) {
    __shared__ float sm[256], ss[256];
    int col = blockIdx.x;
    int t = threadIdx.x;
    float m = -3.4e38f, s = 0.f;
    for (int c = t; c < 782; c += 256) {
        float m2 = pm[col * 782 + c], s2 = ps[col * 782 + c];
        float M = fmaxf(m, m2);
        s = s * __expf(m - M) + s2 * __expf(m2 - M);
        m = M;
    }
    sm[t] = m; ss[t] = s;
    __syncthreads();
    for (int off = 128; off > 0; off >>= 1) {
        if (t < off) {
            float m2 = sm[t + off], s2 = ss[t + off];
            float M = fmaxf(sm[t], m2);
            ss[t] = ss[t] * __expf(sm[t] - M) + s2 * __expf(m2 - M);
            sm[t] = M;
        }
        __syncthreads();
    }
    if (t == 0) { cmg[col] = sm[0]; clg[col] = logf(ss[0]); }
}

// ---- final: element-wise subtract, full grid ----
__global__ void __launch_bounds__(256) final_k(const float* __restrict__ S,
                                               const float* __restrict__ cmg,
                                               const float* __restrict__ clg,
                                               float* __restrict__ out) {
    __shared__ float cc[32];
    int t = threadIdx.x;
    if (t < 32) cc[t] = cmg[t] + clg[t];
    __syncthreads();
    int idx = blockIdx.x * 256 + t;
    if (idx < N_NODES * 32) {
        int b = idx & 31;
        out[idx] = S[idx] - cc[b];
    }
}

extern "C" void kernel_launch(void* const* d_in, const int* in_sizes, int n_in,
                              void* d_out, int out_size, void* d_ws, size_t ws_size,
                              hipStream_t stream) {
    const float* x       = (const float*)d_in[0];
    const int*   ei      = (const int*)d_in[1];
    const float* lh      = (const float*)d_in[2];
    const float* W1_rel  = (const float*)d_in[3];
    const float* W1_root = (const float*)d_in[4];
    const float* b1      = (const float*)d_in[5];
    const float* W2_rel  = (const float*)d_in[6];
    const float* W2_root = (const float*)d_in[7];
    const float* b2      = (const float*)d_in[8];
    const float* Wp      = (const float*)d_in[9];
    const float* bp      = (const float*)d_in[10];
    float* out = (float*)d_out;
    float* ws  = (float*)d_ws;

    // workspace layout (float-element offsets; 16B alignment where needed)
    unsigned short* xb    = (unsigned short*)(ws);              // 3,200,000 fl
    unsigned char*  tbf   = (unsigned char*)(ws + 3200000);     // fp8: 50001*128 B = 1,600,032 fl
    unsigned short* rootb = (unsigned short*)(ws + 4800032);    // 3,200,000 fl
    unsigned short* hb    = (unsigned short*)(ws + 8000032);    // 3,200,000 fl
    unsigned short* Wt1r  = (unsigned short*)(ws + 11200032);   // 8192 fl each
    unsigned short* Wt1o  = (unsigned short*)(ws + 11208224);
    unsigned short* Wt2r  = (unsigned short*)(ws + 11216416);
    unsigned short* Wt2o  = (unsigned short*)(ws + 11224608);
    unsigned short* MEb   = (unsigned short*)(ws + 11232800);   // 2048 fl
    float* pm   = ws + 11234848;                                // 25,024
    float* ps   = ws + 11259872;                                // 25,024
    float* cmg  = ws + 11284896;                                // 32
    float* clg  = ws + 11284928;                                // 32
    int*   cnt  = (int*)(ws + 11284960);                        // 50,000
    int*   prow = (int*)(ws + 11334960);                        // 50,001
    int*   total= (int*)(ws + 11384961);                        // 1
    int*   rank = (int*)(ws + 11384964);                        // 640,000
    unsigned short* ssrc = (unsigned short*)(ws + 12024964);    // 990,000 u16 (16B-aligned)
    float* S    = ws + 12519964;                                // 1,600,000

    const int* srcp = ei;
    const int* dstp = ei + N_EDGES;

    const int e_grid   = (N_EDGES + 255) / 256;      // 2500
    const int ew_grid  = (N_NODES * 32 + 255) / 256; // 6250
    const int agg_grid = (N_NODES + 3) / 4;          // 12500
    const int mm_grid  = (N_NODES + 63) / 64;        // 782

    // 1. fused prep
    prep_k<<<8654, 256, 0, stream>>>((const float4*)x, (ushort4*)xb,
                                     W1_rel, W1_root, W2_rel, W2_root,
                                     Wt1r, Wt1o, Wt2r, Wt2o,
                                     cnt, lh, Wp, bp, MEb, ssrc, tbf, total);

    // 2. histogram + rank
    hist_k<<<e_grid, 256, 0, stream>>>(dstp, cnt, rank);

    // 3. region allocator | layer-1 dual GEMM (independent, merged)
    allocgemm_k<<<196 + mm_grid, 256, 0, stream>>>(cnt, prow, total,
                                                   xb, Wt1r, Wt1o, tbf, rootb);

    // 4. placement
    place_k<<<e_grid, 256, 0, stream>>>(srcp, dstp, prow, rank, ssrc);

    // 5. layer-1 aggregate (fp8 gather)
    agg_k<<<agg_grid, 256, 0, stream>>>(prow, cnt, ssrc, tbf, rootb, b1, hb);

    // 6. layer-2 dual GEMM
    gemm_dual_k<<<mm_grid, 256, 0, stream>>>(hb, Wt2r, Wt2o, tbf, rootb, N_NODES);

    // 7. layer-2 aggregate (fp8 gather)
    agg_k<<<agg_grid, 256, 0, stream>>>(prow, cnt, ssrc, tbf, rootb, b2, hb);

    // 8. scores GEMM + fused per-block column stats
    scores_cs_k<<<mm_grid, 256, 0, stream>>>(hb, MEb, S, pm, ps);

    // 9. merge column stats (32 blocks)
    merge_k<<<32, 256, 0, stream>>>(pm, ps, cmg, clg);

    // 10. final subtract (full grid)
    final_k<<<ew_grid, 256, 0, stream>>>(S, cmg, clg, out);
}

// Round 17
// 279.970 us; speedup vs baseline: 1.0365x; 1.0081x over previous
//
#include <hip/hip_runtime.h>
#include <hip/hip_bf16.h>

#define N_NODES 50000
#define N_EDGES 640000
#define DUMMY   N_NODES
#define PAD_SSRC 990000   // u16 slots; E + 7*N upper bound
// FEAT = EMB = 128, HID = 512, B = 32

typedef __attribute__((ext_vector_type(8))) short short8;   // 8 x bf16 (4 VGPRs)
typedef __attribute__((ext_vector_type(4))) float floatx4;  // MFMA C/D

__device__ __forceinline__ float bf2f(unsigned short u) {
    return __uint_as_float(((unsigned int)u) << 16);
}
__device__ __forceinline__ unsigned short f2bf(float x) {
    unsigned int u = __float_as_uint(x);
    u = (u + 0x7fffu + ((u >> 16) & 1u)) >> 16;   // RNE
    return (unsigned short)u;
}
__device__ __forceinline__ unsigned char f2f8(float x) {
    int pk = __builtin_amdgcn_cvt_pk_fp8_f32(x, x, 0, false);  // OCP e4m3 on gfx950
    return (unsigned char)(pk & 0xff);
}

// ---- fused prep + histogram:
//   x->bf16 | pack weights | message_embed | fill ssrc pad | dummy row/total | hist(+packed rank)
//   cnt must be zeroed by hipMemsetAsync BEFORE this kernel (hist blocks race-free).
__global__ void __launch_bounds__(256) prep_k(const float4* __restrict__ x4,
                                              ushort4* __restrict__ xb4,
                                              const float* __restrict__ W0,
                                              const float* __restrict__ W1,
                                              const float* __restrict__ W2,
                                              const float* __restrict__ W3,
                                              unsigned short* __restrict__ T0,
                                              unsigned short* __restrict__ T1,
                                              unsigned short* __restrict__ T2,
                                              unsigned short* __restrict__ T3,
                                              int* __restrict__ cnt,
                                              const float* __restrict__ lh,
                                              const float* __restrict__ Wp,
                                              const float* __restrict__ bp,
                                              unsigned short* __restrict__ meb,
                                              unsigned short* __restrict__ ssrc,
                                              unsigned char* __restrict__ tbf,
                                              int* __restrict__ total,
                                              const int* __restrict__ dst,
                                              int* __restrict__ rank) {
    int b = blockIdx.x, tid = threadIdx.x;
    if (b < 6250) {                      // cast x to bf16: 1.6M float4
        int i = b * 256 + tid;
        float4 v = x4[i];
        ushort4 o;
        o.x = f2bf(v.x); o.y = f2bf(v.y); o.z = f2bf(v.z); o.w = f2bf(v.w);
        xb4[i] = o;
    } else if (b < 6506) {               // pack weights transposed: 65536
        int idx = (b - 6250) * 256 + tid;
        int w = idx >> 14;
        int r = idx & 16383;
        int n = r >> 7, k = r & 127;
        const float* W = (w == 0) ? W0 : (w == 1) ? W1 : (w == 2) ? W2 : W3;
        unsigned short* T = (w == 0) ? T0 : (w == 1) ? T1 : (w == 2) ? T2 : T3;
        T[r] = f2bf(W[k * 128 + n]);
    } else if (b < 6522) {               // message embed: 4096 outputs
        int o = (b - 6506) * 256 + tid;
        int i = o >> 7, c = o & 127;
        float acc = bp[c];
        const float4* lr = (const float4*)(lh + i * 512);
        #pragma unroll 4
        for (int k4 = 0; k4 < 128; k4++) {
            float4 v = lr[k4];
            acc += v.x * Wp[(4 * k4 + 0) * 128 + c] + v.y * Wp[(4 * k4 + 1) * 128 + c]
                 + v.z * Wp[(4 * k4 + 2) * 128 + c] + v.w * Wp[(4 * k4 + 3) * 128 + c];
        }
        meb[o] = f2bf(acc);
    } else if (b < 8456) {               // fill padded ssrc with DUMMY (u16 pairs): 495000 u32
        int i = (b - 6522) * 256 + tid;
        if (i < PAD_SSRC / 2) ((unsigned int*)ssrc)[i] = 0xC350C350u;
    } else if (b == 8456) {              // zero dummy fp8 row (128 B) + total
        if (tid < 32) ((unsigned int*)(tbf + (size_t)DUMMY * 128))[tid] = 0;
        else if (tid == 32) *total = 0;
    } else {                             // histogram + packed rank: 2500 blocks
        int e = (b - 8457) * 256 + tid;  // exactly 640000
        int d = dst[e];
        int r = atomicAdd(&cnt[d], 1);
        rank[e] = (r << 16) | d;
    }
}

// ---- shared gemm_dual body: Trel = fp8(A@Wrel), Rootb = bf16(A@Wroot) ----
__device__ __forceinline__ void gemm_dual_body(int bid, int tid,
                                               const unsigned short* __restrict__ A,
                                               const unsigned short* __restrict__ BtRel,
                                               const unsigned short* __restrict__ BtRoot,
                                               unsigned char* __restrict__ Trel,
                                               unsigned short* __restrict__ Rootb, int M) {
    int wid = tid >> 6, lane = tid & 63;
    int r0 = bid * 64 + wid * 16;
    int m = lane & 15, g = lane >> 4;
    int row = r0 + m;
    int rowc = (row < M) ? row : (M - 1);
    short8 a[4];
    #pragma unroll
    for (int kt = 0; kt < 4; kt++)
        a[kt] = *(const short8*)(A + (size_t)rowc * 128 + kt * 32 + g * 8);
    floatx4 accR[8], accO[8];
    #pragma unroll
    for (int ct = 0; ct < 8; ct++) {
        accR[ct] = (floatx4)(0.f);
        accO[ct] = (floatx4)(0.f);
    }
    #pragma unroll
    for (int ct = 0; ct < 8; ct++) {
        const unsigned short* br = BtRel  + (size_t)(ct * 16 + m) * 128 + g * 8;
        const unsigned short* bo = BtRoot + (size_t)(ct * 16 + m) * 128 + g * 8;
        #pragma unroll
        for (int kt = 0; kt < 4; kt++) {
            short8 bR = *(const short8*)(br + kt * 32);
            accR[ct] = __builtin_amdgcn_mfma_f32_16x16x32_bf16(a[kt], bR, accR[ct], 0, 0, 0);
            short8 bO = *(const short8*)(bo + kt * 32);
            accO[ct] = __builtin_amdgcn_mfma_f32_16x16x32_bf16(a[kt], bO, accO[ct], 0, 0, 0);
        }
    }
    // C/D layout: col = lane&15, row = (lane>>4)*4 + reg
    #pragma unroll
    for (int ct = 0; ct < 8; ct++) {
        #pragma unroll
        for (int rg = 0; rg < 4; rg++) {
            int ro = r0 + g * 4 + rg;
            if (ro < M) {
                int co = ct * 16 + m;
                Trel[(size_t)ro * 128 + co]  = f2f8(accR[ct][rg]);
                Rootb[(size_t)ro * 128 + co] = f2bf(accO[ct][rg]);
            }
        }
    }
}

// ---- merged: region allocator (blocks 0..195) | layer-1 dual GEMM (blocks 196..977) ----
__global__ void __launch_bounds__(256) allocgemm_k(const int* __restrict__ cnt,
                                                   int* __restrict__ prow,
                                                   int* __restrict__ total,
                                                   const unsigned short* __restrict__ A,
                                                   const unsigned short* __restrict__ BtRel,
                                                   const unsigned short* __restrict__ BtRoot,
                                                   unsigned char* __restrict__ Trel,
                                                   unsigned short* __restrict__ Rootb) {
    if (blockIdx.x < 196) {
        __shared__ int sm[256];
        __shared__ int base_s;
        int t = threadIdx.x;
        int i = blockIdx.x * 256 + t;
        int pc = (i < N_NODES) ? ((cnt[i] + 7) & ~7) : 0;
        sm[t] = pc;
        __syncthreads();
        for (int off = 1; off < 256; off <<= 1) {
            int v = (t >= off) ? sm[t - off] : 0;
            __syncthreads();
            sm[t] += v;
            __syncthreads();
        }
        if (t == 255) base_s = atomicAdd(total, sm[255]);
        __syncthreads();
        if (i < N_NODES) prow[i] = base_s + sm[t] - pc;
    } else {
        gemm_dual_body(blockIdx.x - 196, threadIdx.x, A, BtRel, BtRoot, Trel, Rootb, N_NODES);
    }
}

// ---- placement: packed (rank,dst) -> single stream + prow gather + scatter ----
__global__ void __launch_bounds__(256) place_k(const int* __restrict__ src,
                                               const int* __restrict__ prow,
                                               const int* __restrict__ rank,
                                               unsigned short* __restrict__ ssrc) {
    int e = blockIdx.x * 256 + threadIdx.x;
    if (e < N_EDGES) {
        int pk = rank[e];
        int d = pk & 0xffff;
        int r = pk >> 16;
        ssrc[prow[d] + r] = (unsigned short)src[e];
    }
}

// ---- standalone dual GEMM (layer 2) ----
__global__ void __launch_bounds__(256) gemm_dual_k(const unsigned short* __restrict__ A,
                                                   const unsigned short* __restrict__ BtRel,
                                                   const unsigned short* __restrict__ BtRoot,
                                                   unsigned char* __restrict__ Trel,
                                                   unsigned short* __restrict__ Rootb, int M) {
    gemm_dual_body(blockIdx.x, threadIdx.x, A, BtRel, BtRoot, Trel, Rootb, M);
}

// ---- gather-aggregate v8: fp8 table (128 B row), 2 rows/instr, 16 edges/round ----
__global__ void __launch_bounds__(256) agg_k(const int* __restrict__ prow,
                                             const int* __restrict__ cnt,
                                             const unsigned short* __restrict__ ssrc,
                                             const unsigned char* __restrict__ t,
                                             const unsigned short* __restrict__ rootb,
                                             const float* __restrict__ bias,
                                             unsigned short* __restrict__ hout) {
    int node = blockIdx.x * 4 + (threadIdx.x >> 6);
    if (node >= N_NODES) return;
    int lane = threadIdx.x & 63;
    int fl = lane & 31;                    // feature group (4 feats)
    int sh = (lane & 32) >> 1;             // 0 = even-edge half, 16 = odd-edge half
    int beg = prow[node];
    int deg = cnt[node];
    int endp = beg + ((deg + 7) & ~7);
    const unsigned char* tf = t + fl * 4;
    float a0=0.f,a1=0.f,a2=0.f,a3=0.f;
    float b0=0.f,b1=0.f,b2=0.f,b3=0.f;
    for (int e = beg; e < endp; e += 16) {
        uint4 w0 = *(const uint4*)(ssrc + e);
        uint4 w1 = (e + 8 < endp) ? *(const uint4*)(ssrc + e + 8)
                                  : make_uint4(0xC350C350u, 0xC350C350u, 0xC350C350u, 0xC350C350u);
        int i0 = (int)((w0.x >> sh) & 0xffffu);
        int i1 = (int)((w0.y >> sh) & 0xffffu);
        int i2 = (int)((w0.z >> sh) & 0xffffu);
        int i3 = (int)((w0.w >> sh) & 0xffffu);
        int i4 = (int)((w1.x >> sh) & 0xffffu);
        int i5 = (int)((w1.y >> sh) & 0xffffu);
        int i6 = (int)((w1.z >> sh) & 0xffffu);
        int i7 = (int)((w1.w >> sh) & 0xffffu);
        unsigned int u0 = *(const unsigned int*)(tf + (size_t)i0 * 128);
        unsigned int u1 = *(const unsigned int*)(tf + (size_t)i1 * 128);
        unsigned int u2 = *(const unsigned int*)(tf + (size_t)i2 * 128);
        unsigned int u3 = *(const unsigned int*)(tf + (size_t)i3 * 128);
        unsigned int u4 = *(const unsigned int*)(tf + (size_t)i4 * 128);
        unsigned int u5 = *(const unsigned int*)(tf + (size_t)i5 * 128);
        unsigned int u6 = *(const unsigned int*)(tf + (size_t)i6 * 128);
        unsigned int u7 = *(const unsigned int*)(tf + (size_t)i7 * 128);
        a0 += __builtin_amdgcn_cvt_f32_fp8(u0, 0) + __builtin_amdgcn_cvt_f32_fp8(u1, 0);
        a1 += __builtin_amdgcn_cvt_f32_fp8(u0, 1) + __builtin_amdgcn_cvt_f32_fp8(u1, 1);
        a2 += __builtin_amdgcn_cvt_f32_fp8(u0, 2) + __builtin_amdgcn_cvt_f32_fp8(u1, 2);
        a3 += __builtin_amdgcn_cvt_f32_fp8(u0, 3) + __builtin_amdgcn_cvt_f32_fp8(u1, 3);
        b0 += __builtin_amdgcn_cvt_f32_fp8(u2, 0) + __builtin_amdgcn_cvt_f32_fp8(u3, 0);
        b1 += __builtin_amdgcn_cvt_f32_fp8(u2, 1) + __builtin_amdgcn_cvt_f32_fp8(u3, 1);
        b2 += __builtin_amdgcn_cvt_f32_fp8(u2, 2) + __builtin_amdgcn_cvt_f32_fp8(u3, 2);
        b3 += __builtin_amdgcn_cvt_f32_fp8(u2, 3) + __builtin_amdgcn_cvt_f32_fp8(u3, 3);
        a0 += __builtin_amdgcn_cvt_f32_fp8(u4, 0) + __builtin_amdgcn_cvt_f32_fp8(u5, 0);
        a1 += __builtin_amdgcn_cvt_f32_fp8(u4, 1) + __builtin_amdgcn_cvt_f32_fp8(u5, 1);
        a2 += __builtin_amdgcn_cvt_f32_fp8(u4, 2) + __builtin_amdgcn_cvt_f32_fp8(u5, 2);
        a3 += __builtin_amdgcn_cvt_f32_fp8(u4, 3) + __builtin_amdgcn_cvt_f32_fp8(u5, 3);
        b0 += __builtin_amdgcn_cvt_f32_fp8(u6, 0) + __builtin_amdgcn_cvt_f32_fp8(u7, 0);
        b1 += __builtin_amdgcn_cvt_f32_fp8(u6, 1) + __builtin_amdgcn_cvt_f32_fp8(u7, 1);
        b2 += __builtin_amdgcn_cvt_f32_fp8(u6, 2) + __builtin_amdgcn_cvt_f32_fp8(u7, 2);
        b3 += __builtin_amdgcn_cvt_f32_fp8(u6, 3) + __builtin_amdgcn_cvt_f32_fp8(u7, 3);
    }
    a0 += b0; a1 += b1; a2 += b2; a3 += b3;
    a0 += __shfl_xor(a0, 32);
    a1 += __shfl_xor(a1, 32);
    a2 += __shfl_xor(a2, 32);
    a3 += __shfl_xor(a3, 32);
    if ((lane & 32) == 0) {
        float inv = 1.f / fmaxf((float)deg, 1.f);
        int f = fl * 4;
        ushort4 r = *(const ushort4*)(rootb + (size_t)node * 128 + f);
        float4 bb = *(const float4*)(bias + f);
        ushort4 o;
        o.x = f2bf(fmaxf(a0 * inv + bf2f(r.x) + bb.x, 0.f));
        o.y = f2bf(fmaxf(a1 * inv + bf2f(r.y) + bb.y, 0.f));
        o.z = f2bf(fmaxf(a2 * inv + bf2f(r.z) + bb.z, 0.f));
        o.w = f2bf(fmaxf(a3 * inv + bf2f(r.w) + bb.w, 0.f));
        *(ushort4*)(hout + (size_t)node * 128 + f) = o;
    }
}

// ---- scores MFMA GEMM fused with per-block column stats ----
__global__ void __launch_bounds__(256) scores_cs_k(const unsigned short* __restrict__ A,
                                                   const unsigned short* __restrict__ Bt,
                                                   float* __restrict__ S,
                                                   float* __restrict__ pm,
                                                   float* __restrict__ ps) {
    __shared__ float Sl[64][33];
    __shared__ float sm[256], ss[256];
    int tid = threadIdx.x;
    int wid = tid >> 6, lane = tid & 63;
    int r0 = blockIdx.x * 64 + wid * 16;
    int m = lane & 15, g = lane >> 4;
    int row = r0 + m;
    int rowc = (row < N_NODES) ? row : (N_NODES - 1);
    short8 a[4];
    #pragma unroll
    for (int kt = 0; kt < 4; kt++)
        a[kt] = *(const short8*)(A + (size_t)rowc * 128 + kt * 32 + g * 8);
    floatx4 acc[2];
    acc[0] = (floatx4)(0.f);
    acc[1] = (floatx4)(0.f);
    #pragma unroll
    for (int ct = 0; ct < 2; ct++) {
        const unsigned short* b = Bt + (size_t)(ct * 16 + m) * 128 + g * 8;
        #pragma unroll
        for (int kt = 0; kt < 4; kt++) {
            short8 bv = *(const short8*)(b + kt * 32);
            acc[ct] = __builtin_amdgcn_mfma_f32_16x16x32_bf16(a[kt], bv, acc[ct], 0, 0, 0);
        }
    }
    #pragma unroll
    for (int ct = 0; ct < 2; ct++) {
        #pragma unroll
        for (int rg = 0; rg < 4; rg++) {
            int lr = wid * 16 + g * 4 + rg;
            int ro = r0 + g * 4 + rg;
            Sl[lr][ct * 16 + m] = acc[ct][rg];
            if (ro < N_NODES) S[(size_t)ro * 32 + ct * 16 + m] = acc[ct][rg];
        }
    }
    __syncthreads();
    int col = tid & 31, sub = tid >> 5;
    int blkbase = blockIdx.x * 64;
    float mm = -3.4e38f, s = 0.f;
    for (int r = sub; r < 64; r += 8) {
        if (blkbase + r < N_NODES) {
            float v = Sl[r][col];
            if (v > mm) { s = s * __expf(mm - v) + 1.f; mm = v; }
            else        { s += __expf(v - mm); }
        }
    }
    sm[tid] = mm; ss[tid] = s;
    __syncthreads();
    for (int off = 128; off >= 32; off >>= 1) {
        if (tid < off) {
            float m2 = sm[tid + off], s2 = ss[tid + off];
            float M = fmaxf(sm[tid], m2);
            ss[tid] = ss[tid] * __expf(sm[tid] - M) + s2 * __expf(m2 - M);
            sm[tid] = M;
        }
        __syncthreads();
    }
    if (tid < 32) { pm[tid * 782 + blockIdx.x] = sm[tid]; ps[tid * 782 + blockIdx.x] = ss[tid]; }
}

// ---- merge: one block per column, reduce 782 chunks -> cm/cl[32] ----
__global__ void __launch_bounds__(256) merge_k(const float* __restrict__ pm,
                                               const float* __restrict__ ps,
                                               float* __restrict__ cmg,
                                               float* __restrict__ clg) {
    __shared__ float sm[256], ss[256];
    int col = blockIdx.x;
    int t = threadIdx.x;
    float m = -3.4e38f, s = 0.f;
    for (int c = t; c < 782; c += 256) {
        float m2 = pm[col * 782 + c], s2 = ps[col * 782 + c];
        float M = fmaxf(m, m2);
        s = s * __expf(m - M) + s2 * __expf(m2 - M);
        m = M;
    }
    sm[t] = m; ss[t] = s;
    __syncthreads();
    for (int off = 128; off > 0; off >>= 1) {
        if (t < off) {
            float m2 = sm[t + off], s2 = ss[t + off];
            float M = fmaxf(sm[t], m2);
            ss[t] = ss[t] * __expf(sm[t] - M) + s2 * __expf(m2 - M);
            sm[t] = M;
        }
        __syncthreads();
    }
    if (t == 0) { cmg[col] = sm[0]; clg[col] = logf(ss[0]); }
}

// ---- final: element-wise subtract, full grid ----
__global__ void __launch_bounds__(256) final_k(const float* __restrict__ S,
                                               const float* __restrict__ cmg,
                                               const float* __restrict__ clg,
                                               float* __restrict__ out) {
    __shared__ float cc[32];
    int t = threadIdx.x;
    if (t < 32) cc[t] = cmg[t] + clg[t];
    __syncthreads();
    int idx = blockIdx.x * 256 + t;
    if (idx < N_NODES * 32) {
        int b = idx & 31;
        out[idx] = S[idx] - cc[b];
    }
}

extern "C" void kernel_launch(void* const* d_in, const int* in_sizes, int n_in,
                              void* d_out, int out_size, void* d_ws, size_t ws_size,
                              hipStream_t stream) {
    const float* x       = (const float*)d_in[0];
    const int*   ei      = (const int*)d_in[1];
    const float* lh      = (const float*)d_in[2];
    const float* W1_rel  = (const float*)d_in[3];
    const float* W1_root = (const float*)d_in[4];
    const float* b1      = (const float*)d_in[5];
    const float* W2_rel  = (const float*)d_in[6];
    const float* W2_root = (const float*)d_in[7];
    const float* b2      = (const float*)d_in[8];
    const float* Wp      = (const float*)d_in[9];
    const float* bp      = (const float*)d_in[10];
    float* out = (float*)d_out;
    float* ws  = (float*)d_ws;

    // workspace layout (float-element offsets; 16B alignment where needed)
    unsigned short* xb    = (unsigned short*)(ws);              // 3,200,000 fl
    unsigned char*  tbf   = (unsigned char*)(ws + 3200000);     // fp8: 50001*128 B = 1,600,032 fl
    unsigned short* rootb = (unsigned short*)(ws + 4800032);    // 3,200,000 fl
    unsigned short* hb    = (unsigned short*)(ws + 8000032);    // 3,200,000 fl
    unsigned short* Wt1r  = (unsigned short*)(ws + 11200032);   // 8192 fl each
    unsigned short* Wt1o  = (unsigned short*)(ws + 11208224);
    unsigned short* Wt2r  = (unsigned short*)(ws + 11216416);
    unsigned short* Wt2o  = (unsigned short*)(ws + 11224608);
    unsigned short* MEb   = (unsigned short*)(ws + 11232800);   // 2048 fl
    float* pm   = ws + 11234848;                                // 25,024
    float* ps   = ws + 11259872;                                // 25,024
    float* cmg  = ws + 11284896;                                // 32
    float* clg  = ws + 11284928;                                // 32
    int*   cnt  = (int*)(ws + 11284960);                        // 50,000
    int*   prow = (int*)(ws + 11334960);                        // 50,001
    int*   total= (int*)(ws + 11384961);                        // 1
    int*   rank = (int*)(ws + 11384964);                        // 640,000 (packed rank<<16|dst)
    unsigned short* ssrc = (unsigned short*)(ws + 12024964);    // 990,000 u16 (16B-aligned)
    float* S    = ws + 12519964;                                // 1,600,000

    const int* srcp = ei;
    const int* dstp = ei + N_EDGES;

    const int e_grid   = (N_EDGES + 255) / 256;      // 2500
    const int ew_grid  = (N_NODES * 32 + 255) / 256; // 6250
    const int agg_grid = (N_NODES + 3) / 4;          // 12500
    const int mm_grid  = (N_NODES + 63) / 64;        // 782

    // 0. zero cnt (graph memset node) — prerequisite for the hist blocks in prep_k
    hipMemsetAsync(cnt, 0, N_NODES * sizeof(int), stream);

    // 1. fused prep + histogram (hist depends only on cnt==0 and input dst)
    prep_k<<<8457 + e_grid, 256, 0, stream>>>((const float4*)x, (ushort4*)xb,
                                              W1_rel, W1_root, W2_rel, W2_root,
                                              Wt1r, Wt1o, Wt2r, Wt2o,
                                              cnt, lh, Wp, bp, MEb, ssrc, tbf, total,
                                              dstp, rank);

    // 2. region allocator | layer-1 dual GEMM (independent, merged)
    allocgemm_k<<<196 + mm_grid, 256, 0, stream>>>(cnt, prow, total,
                                                   xb, Wt1r, Wt1o, tbf, rootb);

    // 3. placement (packed rank stream)
    place_k<<<e_grid, 256, 0, stream>>>(srcp, prow, rank, ssrc);

    // 4. layer-1 aggregate (fp8 gather)
    agg_k<<<agg_grid, 256, 0, stream>>>(prow, cnt, ssrc, tbf, rootb, b1, hb);

    // 5. layer-2 dual GEMM
    gemm_dual_k<<<mm_grid, 256, 0, stream>>>(hb, Wt2r, Wt2o, tbf, rootb, N_NODES);

    // 6. layer-2 aggregate (fp8 gather)
    agg_k<<<agg_grid, 256, 0, stream>>>(prow, cnt, ssrc, tbf, rootb, b2, hb);

    // 7. scores GEMM + fused per-block column stats
    scores_cs_k<<<mm_grid, 256, 0, stream>>>(hb, MEb, S, pm, ps);

    // 8. merge column stats (32 blocks)
    merge_k<<<32, 256, 0, stream>>>(pm, ps, cmg, clg);

    // 9. final subtract (full grid)
    final_k<<<ew_grid, 256, 0, stream>>>(S, cmg, clg, out);
}